// Round 14
// baseline (161.470 us; speedup 1.0000x reference)
//
#include <hip/hip_runtime.h>
#include <hip/hip_bf16.h>

// GAT layer for MI355X (gfx950). FP32 in/out.
// R13 post-mortem: flash7 fused pack+PV at the right access shape (>=512B per
// instruction) but bulk-serialized phases: each super's 256KB adj burst fully
// drains (syncthreads vmcnt(0)) before B-staging before compute -> ~45% HBM
// util. flash8 = 8 uniform windows (k=128): issue next window's adj to REGS
// (2 rows x 512B per int4 inst), stage B, raw lgkm-only barrier (adj stays in
// flight across it), compute 4 MFMA steps, then pack adj regs into the mask
// double-buffer. Continuous issue, no vmcnt drain in the loop.
// Pipeline (3 dispatches): wh(+f12, inline W split) -> flash8 -> reduce.

typedef __bf16 bf16;
typedef __attribute__((ext_vector_type(8))) __bf16 bf16x8;
typedef __attribute__((ext_vector_type(4))) float f32x4;

#define NN 8192
#define F_IN 256
#define F_OUT 128
#define LOG2E 1.44269504088896f
#define ALPHA 0.2f
#define KSLICES 8

__device__ __forceinline__ void split8(const float* __restrict__ p,
                                       bf16x8& hi, bf16x8& lo) {
    const float4 u = *(const float4*)p;
    const float4 v = *(const float4*)(p + 4);
    float f[8] = {u.x, u.y, u.z, u.w, v.x, v.y, v.z, v.w};
#pragma unroll
    for (int j = 0; j < 8; ++j) {
        const bf16 h = (bf16)f[j];
        hi[j] = h;
        lo[j] = (bf16)(f[j] - (float)h);
    }
}

// ---------------------------------------------------------------------------
// K1: Wh = h @ W^T (split-bf16 both operands, fp32 acc) -> WhT bf16 [128][8192];
// f1/f2 computed in-block from the fp32 acc (16-lane shuffle reduce).
// ---------------------------------------------------------------------------
__global__ __launch_bounds__(128) void gat_wh(const float* __restrict__ h,
                                              const float* __restrict__ W,
                                              const float* __restrict__ a,
                                              bf16* __restrict__ WhT,
                                              float* __restrict__ f1L,
                                              float* __restrict__ f2L) {
    const int tid = threadIdx.x;
    const int wv = tid >> 6;
    const int l15 = tid & 15;
    const int g = (tid & 63) >> 4;
    const int rowbase = blockIdx.x * 32 + wv * 16;

    f32x4 acc[8];
    const f32x4 zz = {0.f, 0.f, 0.f, 0.f};
#pragma unroll
    for (int nf = 0; nf < 8; ++nf) acc[nf] = zz;

#pragma unroll
    for (int ks = 0; ks < 8; ++ks) {
        const int k = ks * 32 + g * 8;
        bf16x8 ah, al;
        split8(h + (size_t)(rowbase + l15) * F_IN + k, ah, al);
#pragma unroll
        for (int nf = 0; nf < 8; ++nf) {
            bf16x8 bh, bl;
            split8(W + (size_t)(nf * 16 + l15) * F_IN + k, bh, bl);
            acc[nf] = __builtin_amdgcn_mfma_f32_16x16x32_bf16(ah, bh, acc[nf], 0, 0, 0);
            acc[nf] = __builtin_amdgcn_mfma_f32_16x16x32_bf16(ah, bl, acc[nf], 0, 0, 0);
            acc[nf] = __builtin_amdgcn_mfma_f32_16x16x32_bf16(al, bh, acc[nf], 0, 0, 0);
        }
    }

#pragma unroll
    for (int nf = 0; nf < 8; ++nf)
#pragma unroll
        for (int r = 0; r < 4; ++r)
            WhT[(size_t)(nf * 16 + l15) * NN + rowbase + g * 4 + r] = (bf16)acc[nf][r];

    float a1c[8], a2c[8];
#pragma unroll
    for (int nf = 0; nf < 8; ++nf) {
        a1c[nf] = a[nf * 16 + l15];
        a2c[nf] = a[F_OUT + nf * 16 + l15];
    }
#pragma unroll
    for (int r = 0; r < 4; ++r) {
        float s1 = 0.f, s2 = 0.f;
#pragma unroll
        for (int nf = 0; nf < 8; ++nf) {
            s1 += acc[nf][r] * a1c[nf];
            s2 += acc[nf][r] * a2c[nf];
        }
        s1 += __shfl_xor(s1, 1, 16);
        s1 += __shfl_xor(s1, 2, 16);
        s1 += __shfl_xor(s1, 4, 16);
        s1 += __shfl_xor(s1, 8, 16);
        s2 += __shfl_xor(s2, 1, 16);
        s2 += __shfl_xor(s2, 2, 16);
        s2 += __shfl_xor(s2, 4, 16);
        s2 += __shfl_xor(s2, 8, 16);
        if (l15 == 0) {
            f1L[rowbase + g * 4 + r] = s1 * LOG2E;
            f2L[rowbase + g * 4 + r] = s2 * LOG2E;
        }
    }
}

// ---------------------------------------------------------------------------
// K2: flash8 — window-pipelined fused adj-pack + masked softmax + PV.
// Grid 512 = 64 row-tiles(128 rows) x 8 k-slices(1024 k). 512 thr, 8 waves;
// wave = 16 rows x 128 F_OUT-cols. 8 windows of k=128:
//   [lgkm barrier] [issue adj(w+1) -> 8 int4 regs (2 rows x 512B / inst);
//    stage B(w) 32KB lane-contiguous -> swizzled LDS] [lgkm barrier, adj
//    STAYS IN FLIGHT] [4 MFMA steps: mask byte + f2 from LDS -> 8 exp -> pa;
//    8 ds_read_b128 + 8 MFMA] [pack adj regs -> mask dbuf (w+1)&1].
// LDS 41984 B. Epilogue via accL -> contiguous fp32 writes. Partials over ks.
// ---------------------------------------------------------------------------
#define MOFF(P) (32768 + (P) * 2560)  // mask dbuf: [128 rows][20B padded]
#define FOFF 37888                    // f2 slice (1024 f32)

#define LOADW(W)                                                                 \
    do {                                                                         \
        const int* ap_ = adj + (size_t)(row0 + wv * 16 + half) * NN + kbase +    \
                         (W) * 128 + lane32 * 4;                                 \
        _Pragma("unroll") for (int i = 0; i < 8; ++i)                            \
            A[i] = *(const int4*)(ap_ + (size_t)(2 * i) * NN);                   \
    } while (0)

#define PACKW(P)                                                                 \
    do {                                                                         \
        _Pragma("unroll") for (int i = 0; i < 8; ++i) {                          \
            const unsigned int n_ = (A[i].x > 0 ? 1u : 0u) | (A[i].y > 0 ? 2u : 0u) | \
                                    (A[i].z > 0 ? 4u : 0u) | (A[i].w > 0 ? 8u : 0u);  \
            const unsigned int o_ = __shfl_xor(n_, 1);                           \
            if ((l & 1) == 0)                                                    \
                *(unsigned char*)(lds + MOFF(P) + (wv * 16 + 2 * i + half) * 20 + \
                                  (lane32 >> 1)) = (unsigned char)(n_ | (o_ << 4)); \
        }                                                                        \
    } while (0)

__global__ __launch_bounds__(512, 4) void gat_flash8(
        const int* __restrict__ adj,
        const bf16* __restrict__ WhT,
        const float* __restrict__ f1L,
        const float* __restrict__ f2L,
        float* __restrict__ O_part,
        float* __restrict__ rs_part) {
    __shared__ __align__(16) char lds[41984];
    // [0,32768): B window [128c][128k] swizzled
    // [32768,37888): mask dbuf 2 x [128 rows][20B]
    // [37888,41984): f2 slice
    // epilogue reuse: accL[64][132] f32 at offset 0

    const int tid = threadIdx.x;
    const int wv = tid >> 6;
    const int l = tid & 63;
    const int l15 = l & 15;
    const int g = l >> 4;
    const int half = l >> 5;    // staging: row of the pair
    const int lane32 = l & 31;  // staging: 16B column unit
    const int rb = blockIdx.x >> 3;
    const int ks = blockIdx.x & 7;
    const int row0 = rb * 128;
    const int kbase = ks * 1024;
    const int lrow = wv * 16 + l15;

    const float f1a = f1L[row0 + lrow];

    f32x4 acc[8];
    const f32x4 zz = {0.f, 0.f, 0.f, 0.f};
#pragma unroll
    for (int nf = 0; nf < 8; ++nf) acc[nf] = zz;
    float rs0 = 0.f;

    // f2 slice -> LDS
    {
        const float2 v = *(const float2*)(f2L + kbase + tid * 2);
        *(float2*)(lds + FOFF + tid * 8) = v;
    }

    int4 A[8];
    // prologue: window 0's adj -> regs -> mask buf 0
    LOADW(0);
    PACKW(0);

    for (int w = 0; w < 8; ++w) {
        // window top: prev B consumed; mask buf[w&1] writes visible
        asm volatile("s_waitcnt lgkmcnt(0)" ::: "memory");
        __builtin_amdgcn_s_barrier();
        __builtin_amdgcn_sched_barrier(0);

        // issue next window's adj (held in regs through the whole window)
        if (w < 7) LOADW(w + 1);

        // stage B window [128c][128k], lane-contiguous, swizzled
#pragma unroll
        for (int j = 0; j < 4; ++j) {
            const int u = j * 512 + tid;
            const int cc = u >> 4;
            const int ku = u & 15;
            const bf16x8 v =
                *(const bf16x8*)(WhT + (size_t)cc * NN + kbase + w * 128 + ku * 8);
            *(bf16x8*)(lds + ((cc * 256 + ku * 16) ^ ((cc & 7) << 4))) = v;
        }

        // B visible; adj loads remain in flight (lgkm-only wait)
        asm volatile("s_waitcnt lgkmcnt(0)" ::: "memory");
        __builtin_amdgcn_s_barrier();
        __builtin_amdgcn_sched_barrier(0);

        // 4 MFMA steps (k=32 each)
#pragma unroll
        for (int s = 0; s < 4; ++s) {
            const int tt = w * 4 + s;
            const unsigned int mb =
                *(const unsigned char*)(lds + MOFF(w & 1) + lrow * 20 + s * 4 + g);
            const float4 fa = *(const float4*)(lds + FOFF + tt * 128 + g * 32);
            const float4 fb = *(const float4*)(lds + FOFF + tt * 128 + g * 32 + 16);
            const float ff[8] = {fa.x, fa.y, fa.z, fa.w, fb.x, fb.y, fb.z, fb.w};

            bf16x8 pa;
#pragma unroll
            for (int j = 0; j < 8; ++j) {
                const float x = f1a + ff[j];
                const float e = __builtin_amdgcn_exp2f(fmaxf(x, ALPHA * x));
                pa[j] = (bf16)((mb & (1u << j)) ? e : 0.f);
            }
#pragma unroll
            for (int j = 0; j < 8; ++j) rs0 += (float)pa[j];

            __builtin_amdgcn_s_setprio(1);
#pragma unroll
            for (int nf = 0; nf < 8; ++nf) {
                const int c = nf * 16 + l15;
                const bf16x8 bh = *(const bf16x8*)(
                    lds + ((c * 256 + s * 64 + g * 16) ^ ((c & 7) << 4)));
                acc[nf] = __builtin_amdgcn_mfma_f32_16x16x32_bf16(pa, bh, acc[nf], 0, 0, 0);
            }
            __builtin_amdgcn_s_setprio(0);
        }

        // pack next window's adj into the other mask buffer
        if (w < 7) PACKW((w + 1) & 1);
    }

    // rowsum partial (combine the 4 g-groups)
    rs0 += __shfl_xor(rs0, 16);
    rs0 += __shfl_xor(rs0, 32);
    if (l < 16) rs_part[(size_t)ks * NN + row0 + lrow] = rs0;

    // ---- epilogue: two halves through accL[64][132], contiguous writes ----
    float* accL = (float*)lds;
#pragma unroll
    for (int hh = 0; hh < 2; ++hh) {
        __syncthreads();
        if ((wv >> 2) == hh) {
            const int rbase = (wv & 3) * 16;
#pragma unroll
            for (int nf = 0; nf < 8; ++nf)
#pragma unroll
                for (int r = 0; r < 4; ++r)
                    accL[(rbase + g * 4 + r) * 132 + nf * 16 + l15] = acc[nf][r];
        }
        __syncthreads();
        const int rr = tid >> 3;
        const int seg = tid & 7;
        float* dst = O_part + ((size_t)ks << 20) +
                     (size_t)(row0 + hh * 64 + rr) * F_OUT + seg * 16;
        const float* src = accL + rr * 132 + seg * 16;
        *(float4*)(dst + 0) = *(const float4*)(src + 0);
        *(float4*)(dst + 4) = *(const float4*)(src + 4);
        *(float4*)(dst + 8) = *(const float4*)(src + 8);
        *(float4*)(dst + 12) = *(const float4*)(src + 12);
    }
}

// ---------------------------------------------------------------------------
// K3: reduce k-slices: out = (sum_s O_part[s]) / (sum_s rs_part[s]).
// ---------------------------------------------------------------------------
__global__ __launch_bounds__(256) void gat_reduce(const float* __restrict__ O_part,
                                                  const float* __restrict__ rs_part,
                                                  float* __restrict__ out) {
    const int idx = blockIdx.x * 256 + threadIdx.x;
    const int r = idx >> 5;
    const int c = (idx & 31) * 4;
    float rsum = 0.f;
#pragma unroll
    for (int s = 0; s < KSLICES; ++s) rsum += rs_part[(size_t)s * NN + r];
    float4 o = {0.f, 0.f, 0.f, 0.f};
#pragma unroll
    for (int s = 0; s < KSLICES; ++s) {
        const float4 v =
            *(const float4*)(O_part + ((size_t)s << 20) + (size_t)r * F_OUT + c);
        o.x += v.x;
        o.y += v.y;
        o.z += v.z;
        o.w += v.w;
    }
    const float inv = 1.0f / rsum;
    o.x *= inv;
    o.y *= inv;
    o.z *= inv;
    o.w *= inv;
    *(float4*)(out + (size_t)r * F_OUT + c) = o;
}

// ---------------------------------------------------------------------------
extern "C" void kernel_launch(void* const* d_in, const int* in_sizes, int n_in,
                              void* d_out, int out_size, void* d_ws, size_t ws_size,
                              hipStream_t stream) {
    const float* h = (const float*)d_in[0];  // (8192, 256) fp32
    const int* adj = (const int*)d_in[1];    // (8192, 8192) int32
    const float* W = (const float*)d_in[2];  // (128, 256) fp32
    const float* a = (const float*)d_in[3];  // (1, 256) fp32
    float* out = (float*)d_out;              // (8192, 128) fp32

    char* ws = (char*)d_ws;
    const size_t MB = 1024 * 1024;
    bf16* WhT = (bf16*)ws;                   // 2 MB
    float* f1L = (float*)(ws + 2 * MB);      // 32 KB
    float* f2L = f1L + NN;                   // 32 KB
    float* rs_part = (float*)(ws + 3 * MB);  // 256 KB
    float* O_part = (float*)(ws + 4 * MB);   // 32 MB

    gat_wh<<<256, 128, 0, stream>>>(h, W, a, WhT, f1L, f2L);
    gat_flash8<<<512, 512, 0, stream>>>(adj, WhT, f1L, f2L, O_part, rs_part);
    gat_reduce<<<NN * F_OUT / 4 / 256, 256, 0, stream>>>(O_part, rs_part, out);
}

// Round 15
// 159.021 us; speedup vs baseline: 1.0154x; 1.0154x over previous
//
#include <hip/hip_runtime.h>
#include <hip/hip_bf16.h>

// GAT layer for MI355X (gfx950). FP32 in/out.
// R14 post-mortem: flash8 issued adj BEFORE B's global loads; B's ds_writes
// must wait for B data, and in-order vmcnt retirement therefore drained the
// OLDER adj loads too -> full adj service serialized at every window's
// B-staging (1.2 TB/s). flash9 reorders ONE thing: B loads -> regs FIRST,
// adj loads SECOND, ds_writes THIRD (counted vmcnt(8) leaves adj in flight;
// adj waited only at end-of-window PACKW, a full compute phase later).
// Pipeline (3 dispatches): wh(+f12, inline W split) -> flash9 -> reduce.

typedef __bf16 bf16;
typedef __attribute__((ext_vector_type(8))) __bf16 bf16x8;
typedef __attribute__((ext_vector_type(4))) float f32x4;

#define NN 8192
#define F_IN 256
#define F_OUT 128
#define LOG2E 1.44269504088896f
#define ALPHA 0.2f
#define KSLICES 8

__device__ __forceinline__ void split8(const float* __restrict__ p,
                                       bf16x8& hi, bf16x8& lo) {
    const float4 u = *(const float4*)p;
    const float4 v = *(const float4*)(p + 4);
    float f[8] = {u.x, u.y, u.z, u.w, v.x, v.y, v.z, v.w};
#pragma unroll
    for (int j = 0; j < 8; ++j) {
        const bf16 h = (bf16)f[j];
        hi[j] = h;
        lo[j] = (bf16)(f[j] - (float)h);
    }
}

// ---------------------------------------------------------------------------
// K1: Wh = h @ W^T (split-bf16 both operands, fp32 acc) -> WhT bf16 [128][8192];
// f1/f2 computed in-block from the fp32 acc (16-lane shuffle reduce).
// ---------------------------------------------------------------------------
__global__ __launch_bounds__(128) void gat_wh(const float* __restrict__ h,
                                              const float* __restrict__ W,
                                              const float* __restrict__ a,
                                              bf16* __restrict__ WhT,
                                              float* __restrict__ f1L,
                                              float* __restrict__ f2L) {
    const int tid = threadIdx.x;
    const int wv = tid >> 6;
    const int l15 = tid & 15;
    const int g = (tid & 63) >> 4;
    const int rowbase = blockIdx.x * 32 + wv * 16;

    f32x4 acc[8];
    const f32x4 zz = {0.f, 0.f, 0.f, 0.f};
#pragma unroll
    for (int nf = 0; nf < 8; ++nf) acc[nf] = zz;

#pragma unroll
    for (int ks = 0; ks < 8; ++ks) {
        const int k = ks * 32 + g * 8;
        bf16x8 ah, al;
        split8(h + (size_t)(rowbase + l15) * F_IN + k, ah, al);
#pragma unroll
        for (int nf = 0; nf < 8; ++nf) {
            bf16x8 bh, bl;
            split8(W + (size_t)(nf * 16 + l15) * F_IN + k, bh, bl);
            acc[nf] = __builtin_amdgcn_mfma_f32_16x16x32_bf16(ah, bh, acc[nf], 0, 0, 0);
            acc[nf] = __builtin_amdgcn_mfma_f32_16x16x32_bf16(ah, bl, acc[nf], 0, 0, 0);
            acc[nf] = __builtin_amdgcn_mfma_f32_16x16x32_bf16(al, bh, acc[nf], 0, 0, 0);
        }
    }

#pragma unroll
    for (int nf = 0; nf < 8; ++nf)
#pragma unroll
        for (int r = 0; r < 4; ++r)
            WhT[(size_t)(nf * 16 + l15) * NN + rowbase + g * 4 + r] = (bf16)acc[nf][r];

    float a1c[8], a2c[8];
#pragma unroll
    for (int nf = 0; nf < 8; ++nf) {
        a1c[nf] = a[nf * 16 + l15];
        a2c[nf] = a[F_OUT + nf * 16 + l15];
    }
#pragma unroll
    for (int r = 0; r < 4; ++r) {
        float s1 = 0.f, s2 = 0.f;
#pragma unroll
        for (int nf = 0; nf < 8; ++nf) {
            s1 += acc[nf][r] * a1c[nf];
            s2 += acc[nf][r] * a2c[nf];
        }
        s1 += __shfl_xor(s1, 1, 16);
        s1 += __shfl_xor(s1, 2, 16);
        s1 += __shfl_xor(s1, 4, 16);
        s1 += __shfl_xor(s1, 8, 16);
        s2 += __shfl_xor(s2, 1, 16);
        s2 += __shfl_xor(s2, 2, 16);
        s2 += __shfl_xor(s2, 4, 16);
        s2 += __shfl_xor(s2, 8, 16);
        if (l15 == 0) {
            f1L[rowbase + g * 4 + r] = s1 * LOG2E;
            f2L[rowbase + g * 4 + r] = s2 * LOG2E;
        }
    }
}

// ---------------------------------------------------------------------------
// K2: flash9 — window-pipelined fused adj-pack + masked softmax + PV.
// Grid 512 = 64 row-tiles(128 rows) x 8 k-slices(1024 k). 512 thr, 8 waves;
// wave = 16 rows x 128 F_OUT-cols. 8 windows of k=128. Per window:
//   [lgkm barrier] [B(w) global -> regs (4x16B lane-contiguous)]
//   [adj(w+1) -> 8 int4 regs (2 rows x 512B / inst), ISSUED AFTER B]
//   [ds_write B (counted vmcnt leaves adj in flight)] [lgkm barrier]
//   [4 MFMA steps: mask byte + f2 (LDS) -> 8 exp -> pa; 8 ds_read + 8 MFMA]
//   [PACKW: adj regs -> mask dbuf — first wait on adj, a full phase later].
// ---------------------------------------------------------------------------
#define MOFF(P) (32768 + (P) * 2560)  // mask dbuf: [128 rows][20B padded]
#define FOFF 37888                    // f2 slice (1024 f32)

#define LOADW(W)                                                                 \
    do {                                                                         \
        const int* ap_ = adj + (size_t)(row0 + wv * 16 + half) * NN + kbase +    \
                         (W) * 128 + lane32 * 4;                                 \
        _Pragma("unroll") for (int i = 0; i < 8; ++i)                            \
            A[i] = *(const int4*)(ap_ + (size_t)(2 * i) * NN);                   \
    } while (0)

#define PACKW(P)                                                                 \
    do {                                                                         \
        _Pragma("unroll") for (int i = 0; i < 8; ++i) {                          \
            const unsigned int n_ = (A[i].x > 0 ? 1u : 0u) | (A[i].y > 0 ? 2u : 0u) | \
                                    (A[i].z > 0 ? 4u : 0u) | (A[i].w > 0 ? 8u : 0u);  \
            const unsigned int o_ = __shfl_xor(n_, 1);                           \
            if ((l & 1) == 0)                                                    \
                *(unsigned char*)(lds + MOFF(P) + (wv * 16 + 2 * i + half) * 20 + \
                                  (lane32 >> 1)) = (unsigned char)(n_ | (o_ << 4)); \
        }                                                                        \
    } while (0)

__global__ __launch_bounds__(512, 4) void gat_flash9(
        const int* __restrict__ adj,
        const bf16* __restrict__ WhT,
        const float* __restrict__ f1L,
        const float* __restrict__ f2L,
        float* __restrict__ O_part,
        float* __restrict__ rs_part) {
    __shared__ __align__(16) char lds[41984];
    // [0,32768): B window [128c][128k] swizzled
    // [32768,37888): mask dbuf 2 x [128 rows][20B]
    // [37888,41984): f2 slice
    // epilogue reuse: accL[64][132] f32 at offset 0

    const int tid = threadIdx.x;
    const int wv = tid >> 6;
    const int l = tid & 63;
    const int l15 = l & 15;
    const int g = l >> 4;
    const int half = l >> 5;    // staging: row of the pair
    const int lane32 = l & 31;  // staging: 16B column unit
    const int rb = blockIdx.x >> 3;
    const int ks = blockIdx.x & 7;
    const int row0 = rb * 128;
    const int kbase = ks * 1024;
    const int lrow = wv * 16 + l15;

    const float f1a = f1L[row0 + lrow];

    // B staging addresses (lane-contiguous units)
    int bcc[4], bku[4];
#pragma unroll
    for (int j = 0; j < 4; ++j) {
        const int u = j * 512 + tid;
        bcc[j] = u >> 4;
        bku[j] = u & 15;
    }

    f32x4 acc[8];
    const f32x4 zz = {0.f, 0.f, 0.f, 0.f};
#pragma unroll
    for (int nf = 0; nf < 8; ++nf) acc[nf] = zz;
    float rs0 = 0.f;

    // f2 slice -> LDS
    {
        const float2 v = *(const float2*)(f2L + kbase + tid * 2);
        *(float2*)(lds + FOFF + tid * 8) = v;
    }

    int4 A[8];
    // prologue: window 0's adj -> regs -> mask buf 0
    LOADW(0);
    PACKW(0);

    for (int w = 0; w < 8; ++w) {
        // window top: prev B consumed; mask buf[w&1] writes visible
        asm volatile("s_waitcnt lgkmcnt(0)" ::: "memory");
        __builtin_amdgcn_s_barrier();
        __builtin_amdgcn_sched_barrier(0);

        // ---- phase 1: B(w) global loads -> regs (OLDEST in vmcnt queue) ----
        bf16x8 bv[4];
#pragma unroll
        for (int j = 0; j < 4; ++j)
            bv[j] = *(const bf16x8*)(WhT + (size_t)bcc[j] * NN + kbase + w * 128 +
                                     bku[j] * 8);
        __builtin_amdgcn_sched_barrier(0);

        // ---- phase 2: adj(w+1) loads (YOUNGER; stay in flight past B wait) ----
        if (w < 7) LOADW(w + 1);
        __builtin_amdgcn_sched_barrier(0);

        // ---- phase 3: ds_write B (counted vmcnt: waits B only) ----
#pragma unroll
        for (int j = 0; j < 4; ++j)
            *(bf16x8*)(lds + ((bcc[j] * 256 + bku[j] * 16) ^ ((bcc[j] & 7) << 4))) =
                bv[j];
        __builtin_amdgcn_sched_barrier(0);

        // B visible; adj loads remain in flight (lgkm-only wait)
        asm volatile("s_waitcnt lgkmcnt(0)" ::: "memory");
        __builtin_amdgcn_s_barrier();
        __builtin_amdgcn_sched_barrier(0);

        // ---- 4 MFMA steps (k=32 each) ----
#pragma unroll
        for (int s = 0; s < 4; ++s) {
            const int tt = w * 4 + s;
            const unsigned int mb =
                *(const unsigned char*)(lds + MOFF(w & 1) + lrow * 20 + s * 4 + g);
            const float4 fa = *(const float4*)(lds + FOFF + tt * 128 + g * 32);
            const float4 fb = *(const float4*)(lds + FOFF + tt * 128 + g * 32 + 16);
            const float ff[8] = {fa.x, fa.y, fa.z, fa.w, fb.x, fb.y, fb.z, fb.w};

            bf16x8 pa;
#pragma unroll
            for (int j = 0; j < 8; ++j) {
                const float x = f1a + ff[j];
                const float e = __builtin_amdgcn_exp2f(fmaxf(x, ALPHA * x));
                pa[j] = (bf16)((mb & (1u << j)) ? e : 0.f);
            }
#pragma unroll
            for (int j = 0; j < 8; ++j) rs0 += (float)pa[j];

            __builtin_amdgcn_s_setprio(1);
#pragma unroll
            for (int nf = 0; nf < 8; ++nf) {
                const int c = nf * 16 + l15;
                const bf16x8 bh = *(const bf16x8*)(
                    lds + ((c * 256 + s * 64 + g * 16) ^ ((c & 7) << 4)));
                acc[nf] = __builtin_amdgcn_mfma_f32_16x16x32_bf16(pa, bh, acc[nf], 0, 0, 0);
            }
            __builtin_amdgcn_s_setprio(0);
        }

        // ---- pack next window's adj (first place adj results are needed) ----
        if (w < 7) PACKW((w + 1) & 1);
    }

    // rowsum partial (combine the 4 g-groups)
    rs0 += __shfl_xor(rs0, 16);
    rs0 += __shfl_xor(rs0, 32);
    if (l < 16) rs_part[(size_t)ks * NN + row0 + lrow] = rs0;

    // ---- epilogue: two halves through accL[64][132], contiguous writes ----
    float* accL = (float*)lds;
#pragma unroll
    for (int hh = 0; hh < 2; ++hh) {
        __syncthreads();
        if ((wv >> 2) == hh) {
            const int rbase = (wv & 3) * 16;
#pragma unroll
            for (int nf = 0; nf < 8; ++nf)
#pragma unroll
                for (int r = 0; r < 4; ++r)
                    accL[(rbase + g * 4 + r) * 132 + nf * 16 + l15] = acc[nf][r];
        }
        __syncthreads();
        const int rr = tid >> 3;
        const int seg = tid & 7;
        float* dst = O_part + ((size_t)ks << 20) +
                     (size_t)(row0 + hh * 64 + rr) * F_OUT + seg * 16;
        const float* src = accL + rr * 132 + seg * 16;
        *(float4*)(dst + 0) = *(const float4*)(src + 0);
        *(float4*)(dst + 4) = *(const float4*)(src + 4);
        *(float4*)(dst + 8) = *(const float4*)(src + 8);
        *(float4*)(dst + 12) = *(const float4*)(src + 12);
    }
}

// ---------------------------------------------------------------------------
// K3: reduce k-slices: out = (sum_s O_part[s]) / (sum_s rs_part[s]).
// ---------------------------------------------------------------------------
__global__ __launch_bounds__(256) void gat_reduce(const float* __restrict__ O_part,
                                                  const float* __restrict__ rs_part,
                                                  float* __restrict__ out) {
    const int idx = blockIdx.x * 256 + threadIdx.x;
    const int r = idx >> 5;
    const int c = (idx & 31) * 4;
    float rsum = 0.f;
#pragma unroll
    for (int s = 0; s < KSLICES; ++s) rsum += rs_part[(size_t)s * NN + r];
    float4 o = {0.f, 0.f, 0.f, 0.f};
#pragma unroll
    for (int s = 0; s < KSLICES; ++s) {
        const float4 v =
            *(const float4*)(O_part + ((size_t)s << 20) + (size_t)r * F_OUT + c);
        o.x += v.x;
        o.y += v.y;
        o.z += v.z;
        o.w += v.w;
    }
    const float inv = 1.0f / rsum;
    o.x *= inv;
    o.y *= inv;
    o.z *= inv;
    o.w *= inv;
    *(float4*)(out + (size_t)r * F_OUT + c) = o;
}

// ---------------------------------------------------------------------------
extern "C" void kernel_launch(void* const* d_in, const int* in_sizes, int n_in,
                              void* d_out, int out_size, void* d_ws, size_t ws_size,
                              hipStream_t stream) {
    const float* h = (const float*)d_in[0];  // (8192, 256) fp32
    const int* adj = (const int*)d_in[1];    // (8192, 8192) int32
    const float* W = (const float*)d_in[2];  // (128, 256) fp32
    const float* a = (const float*)d_in[3];  // (1, 256) fp32
    float* out = (float*)d_out;              // (8192, 128) fp32

    char* ws = (char*)d_ws;
    const size_t MB = 1024 * 1024;
    bf16* WhT = (bf16*)ws;                   // 2 MB
    float* f1L = (float*)(ws + 2 * MB);      // 32 KB
    float* f2L = f1L + NN;                   // 32 KB
    float* rs_part = (float*)(ws + 3 * MB);  // 256 KB
    float* O_part = (float*)(ws + 4 * MB);   // 32 MB

    gat_wh<<<256, 128, 0, stream>>>(h, W, a, WhT, f1L, f2L);
    gat_flash9<<<512, 512, 0, stream>>>(adj, WhT, f1L, f2L, O_part, rs_part);
    gat_reduce<<<NN * F_OUT / 4 / 256, 256, 0, stream>>>(O_part, rs_part, out);
}

// Round 16
// 131.421 us; speedup vs baseline: 1.2287x; 1.2100x over previous
//
#include <hip/hip_runtime.h>
#include <hip/hip_bf16.h>

// GAT layer for MI355X (gfx950). FP32 in/out.
// R15 post-mortem: fused adj+PV is structurally capped (~1.4 TB/s) — per
// window the adj service (~6.7kcy/CU) is 10x the compute phase, and the
// window pattern (16 rows x 512B per wave) loses DRAM page locality. The
// split R12 pipeline (126 us) wins: pack's waves march SEQUENTIALLY through
// one 32KB row at 1KB/instruction. This round removes R12's slack:
//   - wh (+f12, inline W split) MERGED into the pack dispatch (independent
//     inputs; pack blocks stream HBM while wh blocks do MFMA elsewhere),
//   - wsplit dispatch gone, 5 dispatches -> 3.
// flash6 + reduce verbatim from R12 (proven).
// Pipeline: whpack -> flash6 -> reduce.

typedef __bf16 bf16;
typedef __attribute__((ext_vector_type(8))) __bf16 bf16x8;
typedef __attribute__((ext_vector_type(4))) float f32x4;

#define NN 8192
#define F_IN 256
#define F_OUT 128
#define LOG2E 1.44269504088896f
#define ALPHA 0.2f
#define KSLICES 8

__device__ __forceinline__ void split8(const float* __restrict__ p,
                                       bf16x8& hi, bf16x8& lo) {
    const float4 u = *(const float4*)p;
    const float4 v = *(const float4*)(p + 4);
    float f[8] = {u.x, u.y, u.z, u.w, v.x, v.y, v.z, v.w};
#pragma unroll
    for (int j = 0; j < 8; ++j) {
        const bf16 h = (bf16)f[j];
        hi[j] = h;
        lo[j] = (bf16)(f[j] - (float)h);
    }
}

// ---------------------------------------------------------------------------
// K1: whpack — one dispatch, two independent jobs.
// blocks 0..2047   : pack adj -> bitmask (R12's lane-contiguous packer).
//                    wave = one row; per iter reads 2x1KB contiguous
//                    (lane i at +16i); nibble + shfl_xor -> mask byte.
//                    maskP[ks][row][128B].
// blocks 2048..2175: Wh = h @ W^T (split-bf16 both operands, fp32 acc)
//                    -> WhT bf16 [128][8192]; f1/f2 from fp32 acc.
//                    256 thr = 4 waves x 16 rows (64 rows/block).
// ---------------------------------------------------------------------------
__global__ __launch_bounds__(256) void gat_whpack(
        const int* __restrict__ adj,
        const float* __restrict__ h,
        const float* __restrict__ W,
        const float* __restrict__ a,
        unsigned char* __restrict__ maskP,
        bf16* __restrict__ WhT,
        float* __restrict__ f1L,
        float* __restrict__ f2L) {
    const int tid = threadIdx.x;

    if (blockIdx.x < 2048) {
        // ---------------- pack ----------------
        const int row = blockIdx.x * 4 + (tid >> 6);
        const int l = tid & 63;
        const int* rowp = adj + (size_t)row * NN;

#pragma unroll 4
        for (int iter = 0; iter < 16; ++iter) {
            const int base = iter * 512;
            const int4 v1 = *(const int4*)(rowp + base + l * 4);
            const int4 v2 = *(const int4*)(rowp + base + 256 + l * 4);
            unsigned int n1 = (v1.x > 0 ? 1u : 0u) | (v1.y > 0 ? 2u : 0u) |
                              (v1.z > 0 ? 4u : 0u) | (v1.w > 0 ? 8u : 0u);
            unsigned int n2 = (v2.x > 0 ? 1u : 0u) | (v2.y > 0 ? 2u : 0u) |
                              (v2.z > 0 ? 4u : 0u) | (v2.w > 0 ? 8u : 0u);
            const unsigned int p1 = __shfl_xor(n1, 1);
            const unsigned int p2 = __shfl_xor(n2, 1);
            if ((l & 1) == 0) {
                const int b1 = iter * 64 + (l >> 1);  // byte index 0..1023
                const int b2 = b1 + 32;
                maskP[((size_t)(b1 >> 7) << 20) + (size_t)row * 128 + (b1 & 127)] =
                    (unsigned char)(n1 | (p1 << 4));
                maskP[((size_t)(b2 >> 7) << 20) + (size_t)row * 128 + (b2 & 127)] =
                    (unsigned char)(n2 | (p2 << 4));
            }
        }
        return;
    }

    // ---------------- wh (+f12) ----------------
    const int wb = blockIdx.x - 2048;  // 0..127
    const int wv = tid >> 6;
    const int l15 = tid & 15;
    const int g = (tid & 63) >> 4;
    const int rowbase = wb * 64 + wv * 16;

    f32x4 acc[8];
    const f32x4 zz = {0.f, 0.f, 0.f, 0.f};
#pragma unroll
    for (int nf = 0; nf < 8; ++nf) acc[nf] = zz;

#pragma unroll
    for (int ks = 0; ks < 8; ++ks) {
        const int k = ks * 32 + g * 8;
        bf16x8 ah, al;
        split8(h + (size_t)(rowbase + l15) * F_IN + k, ah, al);
#pragma unroll
        for (int nf = 0; nf < 8; ++nf) {
            bf16x8 bh, bl;
            split8(W + (size_t)(nf * 16 + l15) * F_IN + k, bh, bl);
            acc[nf] = __builtin_amdgcn_mfma_f32_16x16x32_bf16(ah, bh, acc[nf], 0, 0, 0);
            acc[nf] = __builtin_amdgcn_mfma_f32_16x16x32_bf16(ah, bl, acc[nf], 0, 0, 0);
            acc[nf] = __builtin_amdgcn_mfma_f32_16x16x32_bf16(al, bh, acc[nf], 0, 0, 0);
        }
    }

#pragma unroll
    for (int nf = 0; nf < 8; ++nf)
#pragma unroll
        for (int r = 0; r < 4; ++r)
            WhT[(size_t)(nf * 16 + l15) * NN + rowbase + g * 4 + r] = (bf16)acc[nf][r];

    float a1c[8], a2c[8];
#pragma unroll
    for (int nf = 0; nf < 8; ++nf) {
        a1c[nf] = a[nf * 16 + l15];
        a2c[nf] = a[F_OUT + nf * 16 + l15];
    }
#pragma unroll
    for (int r = 0; r < 4; ++r) {
        float s1 = 0.f, s2 = 0.f;
#pragma unroll
        for (int nf = 0; nf < 8; ++nf) {
            s1 += acc[nf][r] * a1c[nf];
            s2 += acc[nf][r] * a2c[nf];
        }
        s1 += __shfl_xor(s1, 1, 16);
        s1 += __shfl_xor(s1, 2, 16);
        s1 += __shfl_xor(s1, 4, 16);
        s1 += __shfl_xor(s1, 8, 16);
        s2 += __shfl_xor(s2, 1, 16);
        s2 += __shfl_xor(s2, 2, 16);
        s2 += __shfl_xor(s2, 4, 16);
        s2 += __shfl_xor(s2, 8, 16);
        if (l15 == 0) {
            f1L[rowbase + g * 4 + r] = s1 * LOG2E;
            f2L[rowbase + g * 4 + r] = s2 * LOG2E;
        }
    }
}

// ---------------------------------------------------------------------------
// K2: flash6 (verbatim R12). Grid 512 = 64 row-tiles(128 rows) x 8 k-slices.
// 512 thr, 8 waves; wave = 16 rows x 128 cols. 8 chunks of k=128:
//   [sync][stage B 32KB (lane-contiguous, swizzled LDS) + mask 2KB][sync]
//   [4 steps: mask byte + f2 from LDS -> 8 exp -> pa; 8 ds_read_b128 + MFMA]
// 39.4 KB LDS -> 4 blocks/CU. Epilogue via accL -> contiguous fp32 writes.
// ---------------------------------------------------------------------------
__global__ __launch_bounds__(512, 4) void gat_flash6(
        const unsigned char* __restrict__ maskP,
        const bf16* __restrict__ WhT,
        const float* __restrict__ f1L,
        const float* __restrict__ f2L,
        float* __restrict__ O_part,
        float* __restrict__ rs_part) {
    __shared__ __align__(16) char lds[39424];
    // [0,32768): B chunk [128c][128k] swizzled
    // [32768,35328): mask chunk [128 rows][20B padded stride, 16B used]
    // [35328,39424): f2 slice (1024 f32)
    // epilogue reuse: accL[64][132] f32 at offset 0

    const int tid = threadIdx.x;
    const int wv = tid >> 6;
    const int l = tid & 63;
    const int l15 = l & 15;
    const int g = l >> 4;
    const int rb = blockIdx.x >> 3;
    const int ks = blockIdx.x & 7;
    const int row0 = rb * 128;
    const int lrow = wv * 16 + l15;

    const float f1a = f1L[row0 + lrow];

    const int mr = tid >> 2;   // mask staging row
    const int mseg = tid & 3;  // 4B segment
    const unsigned char* msrc =
        maskP + ((size_t)ks << 20) + (size_t)(row0 + mr) * 128 + mseg * 4;

    f32x4 acc[8];
    const f32x4 zz = {0.f, 0.f, 0.f, 0.f};
#pragma unroll
    for (int nf = 0; nf < 8; ++nf) acc[nf] = zz;
    float rs0 = 0.f;

    // f2 slice -> LDS (visible after the first stage barrier pair)
    {
        const float2 v = *(const float2*)(f2L + ks * 1024 + tid * 2);
        *(float2*)(lds + 35328 + tid * 8) = v;
    }

    for (int it = 0; it < 8; ++it) {
        __syncthreads();  // previous chunk fully consumed
        // ---- stage mask chunk (2KB) ----
        const unsigned int mw = *(const unsigned int*)(msrc + it * 16);
        *(unsigned int*)(lds + 32768 + mr * 20 + mseg * 4) = mw;
        // ---- stage B chunk (32KB), lane-contiguous reads, swizzled writes ----
#pragma unroll
        for (int j = 0; j < 4; ++j) {
            const int u = j * 512 + tid;
            const int cc = u >> 4;
            const int ku = u & 15;
            const bf16x8 v =
                *(const bf16x8*)(WhT + (size_t)cc * NN + ks * 1024 + it * 128 + ku * 8);
            *(bf16x8*)(lds + ((cc * 256 + ku * 16) ^ ((cc & 7) << 4))) = v;
        }
        __syncthreads();  // staged data visible

        // ---- 4 MFMA steps (k=32 each) ----
#pragma unroll
        for (int s = 0; s < 4; ++s) {
            const unsigned int mb =
                *(const unsigned char*)(lds + 32768 + lrow * 20 + s * 4 + g);
            const int t = it * 4 + s;
            const float4 fa = *(const float4*)(lds + 35328 + t * 128 + g * 32);
            const float4 fb = *(const float4*)(lds + 35328 + t * 128 + g * 32 + 16);
            const float ff[8] = {fa.x, fa.y, fa.z, fa.w, fb.x, fb.y, fb.z, fb.w};

            bf16x8 pa;
#pragma unroll
            for (int j = 0; j < 8; ++j) {
                const float x = f1a + ff[j];
                const float e = __builtin_amdgcn_exp2f(fmaxf(x, ALPHA * x));
                pa[j] = (bf16)((mb & (1u << j)) ? e : 0.f);
            }
#pragma unroll
            for (int j = 0; j < 8; ++j) rs0 += (float)pa[j];

            __builtin_amdgcn_s_setprio(1);
#pragma unroll
            for (int nf = 0; nf < 8; ++nf) {
                const int c = nf * 16 + l15;
                const bf16x8 bh = *(const bf16x8*)(
                    lds + ((c * 256 + s * 64 + g * 16) ^ ((c & 7) << 4)));
                acc[nf] = __builtin_amdgcn_mfma_f32_16x16x32_bf16(pa, bh, acc[nf], 0, 0, 0);
            }
            __builtin_amdgcn_s_setprio(0);
        }
    }

    // rowsum partial (combine the 4 g-groups)
    rs0 += __shfl_xor(rs0, 16);
    rs0 += __shfl_xor(rs0, 32);
    if (l < 16) rs_part[(size_t)ks * NN + row0 + lrow] = rs0;

    // ---- epilogue: two halves through accL[64][132], contiguous writes ----
    float* accL = (float*)lds;
#pragma unroll
    for (int half = 0; half < 2; ++half) {
        __syncthreads();
        if ((wv >> 2) == half) {
            const int rbase = (wv & 3) * 16;
#pragma unroll
            for (int nf = 0; nf < 8; ++nf)
#pragma unroll
                for (int r = 0; r < 4; ++r)
                    accL[(rbase + g * 4 + r) * 132 + nf * 16 + l15] = acc[nf][r];
        }
        __syncthreads();
        const int rr = tid >> 3;  // 0..63
        const int seg = tid & 7;  // 16 floats each
        float* dst = O_part + ((size_t)ks << 20) +
                     (size_t)(row0 + half * 64 + rr) * F_OUT + seg * 16;
        const float* src = accL + rr * 132 + seg * 16;
        *(float4*)(dst + 0) = *(const float4*)(src + 0);
        *(float4*)(dst + 4) = *(const float4*)(src + 4);
        *(float4*)(dst + 8) = *(const float4*)(src + 8);
        *(float4*)(dst + 12) = *(const float4*)(src + 12);
    }
}

// ---------------------------------------------------------------------------
// K3: reduce k-slices: out = (sum_s O_part[s]) / (sum_s rs_part[s]).
// ---------------------------------------------------------------------------
__global__ __launch_bounds__(256) void gat_reduce(const float* __restrict__ O_part,
                                                  const float* __restrict__ rs_part,
                                                  float* __restrict__ out) {
    const int idx = blockIdx.x * 256 + threadIdx.x;
    const int r = idx >> 5;
    const int c = (idx & 31) * 4;
    float rsum = 0.f;
#pragma unroll
    for (int s = 0; s < KSLICES; ++s) rsum += rs_part[(size_t)s * NN + r];
    float4 o = {0.f, 0.f, 0.f, 0.f};
#pragma unroll
    for (int s = 0; s < KSLICES; ++s) {
        const float4 v =
            *(const float4*)(O_part + ((size_t)s << 20) + (size_t)r * F_OUT + c);
        o.x += v.x;
        o.y += v.y;
        o.z += v.z;
        o.w += v.w;
    }
    const float inv = 1.0f / rsum;
    o.x *= inv;
    o.y *= inv;
    o.z *= inv;
    o.w *= inv;
    *(float4*)(out + (size_t)r * F_OUT + c) = o;
}

// ---------------------------------------------------------------------------
extern "C" void kernel_launch(void* const* d_in, const int* in_sizes, int n_in,
                              void* d_out, int out_size, void* d_ws, size_t ws_size,
                              hipStream_t stream) {
    const float* h = (const float*)d_in[0];  // (8192, 256) fp32
    const int* adj = (const int*)d_in[1];    // (8192, 8192) int32
    const float* W = (const float*)d_in[2];  // (128, 256) fp32
    const float* a = (const float*)d_in[3];  // (1, 256) fp32
    float* out = (float*)d_out;              // (8192, 128) fp32

    char* ws = (char*)d_ws;
    const size_t MB = 1024 * 1024;
    bf16* WhT = (bf16*)ws;                                 // 2 MB
    float* f1L = (float*)(ws + 2 * MB);                    // 32 KB
    float* f2L = f1L + NN;                                 // 32 KB
    unsigned char* maskP = (unsigned char*)(ws + 3 * MB);  // 8 MB [ks][row][128B]
    float* rs_part = (float*)(ws + 11 * MB);               // 256 KB
    float* O_part = (float*)(ws + 12 * MB);                // 32 MB

    gat_whpack<<<2176, 256, 0, stream>>>(adj, h, W, a, maskP, WhT, f1L, f2L);
    gat_flash6<<<512, 512, 0, stream>>>(maskP, WhT, f1L, f2L, O_part, rs_part);
    gat_reduce<<<NN * F_OUT / 4 / 256, 256, 0, stream>>>(O_part, rs_part, out);
}